// Round 7
// baseline (82.600 us; speedup 1.0000x reference)
//
#include <hip/hip_runtime.h>
#include <math.h>

// GraphGenerator: radius-graph adjacency, OR over {0,0.25,0.5,0.75}*domain
// wrapped shifts, diagonal excluded. Output [N,N] int32 0/1.
//
// Golden ("ref=np"): numpy shim of the reference on the container CPU:
//   sq   = ((x*x) + (y*y)) + (z*z)        np.sum: sequential, separately rounded
//   dot  = fma(z,z', fma(y,y', rn(x*x'))) OpenBLAS sgemm: sequential-k FMA chain
//   d2   = rn(rn(sq_i + sq_j) - rn(2*dot))  separate ufuncs
//   pred = d2 <= 0.01f                     f32 weak-promotion of 0.1*0.1
//   wrap = fmodf(rn(x + rn(f*d)), d)       np.remainder, positive args
//
// CRITICAL: '#pragma clang fp contract(off)' in both kernels. HIP's __f*_rn
// are plain-op wrappers; default -ffp-contract=fast silently fused the sq
// chain in R2, which is why this (correct) model appeared to fail.

__global__ __launch_bounds__(256) void gg_shift_kernel(
    const float* __restrict__ pos, const float* __restrict__ dom,
    float4* __restrict__ sp, int n)
{
#pragma clang fp contract(off)
    int i = blockIdx.x * blockDim.x + threadIdx.x;
    if (i >= n) return;
    float x = pos[3 * i + 0];
    float y = pos[3 * i + 1];
    float z = pos[3 * i + 2];
    float dx = dom[0], dy = dom[1], dz = dom[2];
#pragma unroll
    for (int k = 0; k < 4; ++k) {
        float sx, sy, sz;
        if (k == 0) {
            sx = x; sy = y; sz = z;           // pass 1: raw positions
        } else {
            float f = 0.25f * (float)k;       // 0.25, 0.5, 0.75 exact
            sx = fmodf(x + f * dx, dx);       // contract off: add separate
            sy = fmodf(y + f * dy, dy);
            sz = fmodf(z + f * dz, dz);
        }
        // non-FMA sq, left-assoc (np.sum sequential)
        float sq = ((sx * sx) + (sy * sy)) + (sz * sz);
        sp[(size_t)i * 4 + k] = make_float4(sx, sy, sz, sq);
    }
}

// Tile: 32 i-rows x 256 j-cols per 256-thread block.
__global__ __launch_bounds__(256) void gg_adj_kernel(
    const float4* __restrict__ sp, int* __restrict__ out, int n)
{
#pragma clang fp contract(off)
    const int tid = threadIdx.x;
    const int tj = tid & 63;
    const int ti = tid >> 6;
    const int jbase = blockIdx.x * 256 + tj * 4;
    const int ibase = blockIdx.y * 32;

    __shared__ float4 si[32][4];   // 32 i-points x 4 variants (2 KB)
    for (int t = tid; t < 128; t += 256) {
        si[t >> 2][t & 3] = sp[(size_t)(ibase + (t >> 2)) * 4 + (t & 3)];
    }

    float4 jd[4][4];
#pragma unroll
    for (int p = 0; p < 4; ++p)
#pragma unroll
        for (int k = 0; k < 4; ++k)
            jd[p][k] = sp[(size_t)(jbase + p) * 4 + k];

    __syncthreads();

    const float RR = 0.01f;        // f32(0.1*0.1)

    unsigned int acc = 0;          // bit (iter*4 + p)

#pragma unroll
    for (int k = 0; k < 4; ++k) {
#pragma unroll
        for (int iter = 0; iter < 8; ++iter) {
            const int irow = iter * 4 + ti;
            const float4 id = si[irow][k];    // LDS broadcast (x,y,z,sq)
#pragma unroll
            for (int p = 0; p < 4; ++p) {
                // sgemm dot: sequential-k FMA chain, first product only rn'd
                float dot = __builtin_fmaf(id.z, jd[p][k].z,
                            __builtin_fmaf(id.y, jd[p][k].y,
                                           id.x * jd[p][k].x));
                // separate ufuncs: add, (exact) double, sub — contract off
                float d2 = (id.w + jd[p][k].w) - (2.0f * dot);
                if (d2 <= RR) acc |= 1u << (iter * 4 + p);
            }
        }
    }

    // Epilogue: unpack bits, kill diagonal, coalesced int4 stores.
#pragma unroll
    for (int iter = 0; iter < 8; ++iter) {
        const int i = ibase + iter * 4 + ti;
        int4 res;
        res.x = ((acc >> (iter * 4 + 0)) & 1) && (i != jbase + 0) ? 1 : 0;
        res.y = ((acc >> (iter * 4 + 1)) & 1) && (i != jbase + 1) ? 1 : 0;
        res.z = ((acc >> (iter * 4 + 2)) & 1) && (i != jbase + 2) ? 1 : 0;
        res.w = ((acc >> (iter * 4 + 3)) & 1) && (i != jbase + 3) ? 1 : 0;
        *reinterpret_cast<int4*>(&out[(size_t)i * n + jbase]) = res;
    }
}

extern "C" void kernel_launch(void* const* d_in, const int* in_sizes, int n_in,
                              void* d_out, int out_size, void* d_ws, size_t ws_size,
                              hipStream_t stream) {
    const float* pos = (const float*)d_in[0];   // [N,3] float32
    const float* dom = (const float*)d_in[1];   // [3] float32
    const int n = in_sizes[0] / 3;              // 8192

    float4* sp = (float4*)d_ws;                 // [N][4] float4 = 512 KB
    int* out = (int*)d_out;                     // [N,N] int32 0/1

    gg_shift_kernel<<<(n + 255) / 256, 256, 0, stream>>>(pos, dom, sp, n);

    dim3 grid(n / 256, n / 32);                 // (32, 256)
    gg_adj_kernel<<<grid, 256, 0, stream>>>(sp, out, n);
}

// Round 8
// 51.046 us; speedup vs baseline: 1.6181x; 1.6181x over previous
//
#include <hip/hip_runtime.h>
#include <math.h>

// GraphGenerator: radius-graph adjacency, OR over {0,0.25,0.5,0.75}*domain
// wrapped shifts, diagonal excluded. Output [N,N] int32 0/1.
//
// Golden ("ref=np") — PROVEN in R7 (absmax 0):
//   sq   = ((x*x) + (y*y)) + (z*z)          separately rounded (contract off!)
//   dot  = fma(z,z', fma(y,y', rn(x*x')))   sgemm sequential-k FMA chain
//   d2   = rn(rn(sq_i + sq_j) - rn(2*dot))
//   pred = d2 <= 0.01f ; wrap = fmodf(rn(x + rn(f*d)), d)
//
// Optimization: min-image prefilter. Exact min-image d2 lower-bounds every
// variant's d2, and (seam argument: 4 seams spaced 0.25*dom, 3 arcs <= 0.1
// cover <= 3 seams) some variant achieves it. Worst-case f32 chain error
// ~3e-6 << band half-width 3e-5, so outside the band the fast f32 min-image
// decision is identical to the golden OR; inside the band (~2500 pairs total)
// we run the exact R7 chain over all 4 variants.

__global__ __launch_bounds__(256) void gg_shift_kernel(
    const float* __restrict__ pos, const float* __restrict__ dom,
    float4* __restrict__ sp, int n)
{
#pragma clang fp contract(off)
    int i = blockIdx.x * blockDim.x + threadIdx.x;
    if (i >= n) return;
    float x = pos[3 * i + 0];
    float y = pos[3 * i + 1];
    float z = pos[3 * i + 2];
    float dx = dom[0], dy = dom[1], dz = dom[2];
#pragma unroll
    for (int k = 0; k < 4; ++k) {
        float sx, sy, sz;
        if (k == 0) {
            sx = x; sy = y; sz = z;           // pass 1: raw positions
        } else {
            float f = 0.25f * (float)k;       // 0.25, 0.5, 0.75 exact
            sx = fmodf(x + f * dx, dx);       // contract off: add separate
            sy = fmodf(y + f * dy, dy);
            sz = fmodf(z + f * dz, dz);
        }
        // non-FMA sq, left-assoc (np.sum sequential)
        float sq = ((sx * sx) + (sy * sy)) + (sz * sz);
        sp[(size_t)i * 4 + k] = make_float4(sx, sy, sz, sq);
    }
}

// Tile: 32 i-rows x 256 j-cols per 256-thread block.
__global__ __launch_bounds__(256) void gg_adj_kernel(
    const float4* __restrict__ sp, const float* __restrict__ dom,
    int* __restrict__ out, int n)
{
    const int tid = threadIdx.x;
    const int tj = tid & 63;
    const int ti = tid >> 6;
    const int jbase = blockIdx.x * 256 + tj * 4;
    const int ibase = blockIdx.y * 32;

    const float dom0 = dom[0], dom1 = dom[1], dom2 = dom[2];

    __shared__ float4 si[32][4];   // i-tile: 4 variants (slow path needs all)
    for (int t = tid; t < 128; t += 256)
        si[t >> 2][t & 3] = sp[(size_t)(ibase + (t >> 2)) * 4 + (t & 3)];

    // j-side: raw coords + sq only (variant 0); slow path re-reads sp (L2).
    float4 jd0[4];
#pragma unroll
    for (int p = 0; p < 4; ++p)
        jd0[p] = sp[(size_t)(jbase + p) * 4 + 0];

    __syncthreads();

    const float RR = 0.01f;          // f32(0.1*0.1)
    const float LO = 0.01f - 3e-5f;  // fast-accept below
    const float HI = 0.01f + 3e-5f;  // fast-reject above

    for (int iter = 0; iter < 8; ++iter) {
        const int irow = iter * 4 + ti;
        const int i = ibase + irow;
        const float4 i0 = si[irow][0];       // LDS broadcast, raw coords

        int4 res;
        int* r = &res.x;
#pragma unroll
        for (int p = 0; p < 4; ++p) {
            // fast path: f32 min-image d2 (contraction fine, margin absorbs)
            const float ax = fabsf(i0.x - jd0[p].x);
            const float ay = fabsf(i0.y - jd0[p].y);
            const float az = fabsf(i0.z - jd0[p].z);
            const float mx = fminf(ax, dom0 - ax);
            const float my = fminf(ay, dom1 - ay);
            const float mz = fminf(az, dom2 - az);
            const float d2m = mx * mx + my * my + mz * mz;
            bool b = d2m <= RR;
            if (__builtin_expect(d2m >= LO && d2m <= HI, 0)) {
                // band: exact golden chain over all 4 variants (R7-proven)
#pragma clang fp contract(off)
                b = false;
#pragma unroll 1
                for (int k = 0; k < 4; ++k) {
                    const float4 iv = si[irow][k];
                    const float4 jv = sp[(size_t)(jbase + p) * 4 + k];
                    float dot = __builtin_fmaf(iv.z, jv.z,
                                __builtin_fmaf(iv.y, jv.y, iv.x * jv.x));
                    float d2 = (iv.w + jv.w) - (2.0f * dot);
                    if (d2 <= RR) b = true;
                }
            }
            r[p] = (b && (i != jbase + p)) ? 1 : 0;
        }
        *reinterpret_cast<int4*>(&out[(size_t)i * n + jbase]) = res;
    }
}

extern "C" void kernel_launch(void* const* d_in, const int* in_sizes, int n_in,
                              void* d_out, int out_size, void* d_ws, size_t ws_size,
                              hipStream_t stream) {
    const float* pos = (const float*)d_in[0];   // [N,3] float32
    const float* dom = (const float*)d_in[1];   // [3] float32
    const int n = in_sizes[0] / 3;              // 8192

    float4* sp = (float4*)d_ws;                 // [N][4] float4 = 512 KB
    int* out = (int*)d_out;                     // [N,N] int32 0/1

    gg_shift_kernel<<<(n + 255) / 256, 256, 0, stream>>>(pos, dom, sp, n);

    dim3 grid(n / 256, n / 32);                 // (32, 256)
    gg_adj_kernel<<<grid, 256, 0, stream>>>(sp, dom, out, n);
}